// Round 18
// baseline (874.502 us; speedup 1.0000x reference)
//
#include <hip/hip_runtime.h>

// DecoderLayer: rms1 -> QKV -> RoPE -> causal GQA attn -> O+resid -> rms2
// -> noisy top-2 router -> sparse MoE -> resid ; aux loss.
// B=2 S=2048 D=1024 NQ=16 NKV=4 HD=64 E=8 DFF=4096 top_k=2
// r17: 671.7 us (13 launches). r18: attn __launch_bounds__(256,4) caps VGPR
// at 128 (was 132) -> 4 resident blocks/CU instead of 3 (+33% TLP).

#define TKN 4096
#define DM  1024
#define DFF 4096
#define NE  8
#define NEG_INF -3.0e38f
#define BM 128
#define BK 64

typedef __attribute__((ext_vector_type(8))) short short8;
typedef __attribute__((ext_vector_type(4))) float f32x4;

#define MFMA16(a,b,c) __builtin_amdgcn_mfma_f32_16x16x32_bf16(a,b,c,0,0,0)

__device__ __forceinline__ short f2bf(float f){
  union{float f;unsigned u;}v; v.f=f;
  unsigned r=v.u+0x7fffu+((v.u>>16)&1u);
  return (short)(r>>16);
}
__device__ __forceinline__ float bf2f(short s){
  union{unsigned u;float f;}v; v.u=((unsigned)(unsigned short)s)<<16; return v.f;
}
__device__ __forceinline__ void gload16(const short* g, short* l){
  __builtin_amdgcn_global_load_lds(
      (const __attribute__((address_space(1))) void*)g,
      (__attribute__((address_space(3))) void*)l, 16, 0, 0);
}

// ---------------- RMSNorm 1 (+ cnt/imp init in block 0), writes bf16 ----------
__global__ __launch_bounds__(256) void rms1_kernel(const float* __restrict__ x,
    const float* __restrict__ w, short* __restrict__ out,
    int* __restrict__ cnt, float* __restrict__ imp)
{
  const int row=blockIdx.x, tid=threadIdx.x;
  if(row==0 && tid<8){ cnt[tid]=0; imp[tid]=0.f; }
  const float4 xv=((const float4*)(x+(size_t)row*DM))[tid];
  float s=xv.x*xv.x+xv.y*xv.y+xv.z*xv.z+xv.w*xv.w;
  #pragma unroll
  for(int o=32;o;o>>=1) s+=__shfl_down(s,o,64);
  __shared__ float red[4];
  if((tid&63)==0) red[tid>>6]=s;
  __syncthreads();
  float r=rsqrtf((red[0]+red[1]+red[2]+red[3])*(1.f/DM)+1e-8f);
  const float4 wv=((const float4*)w)[tid];
  short* op=out+(size_t)row*DM+tid*4;
  op[0]=f2bf(wv.x*xv.x*r); op[1]=f2bf(wv.y*xv.y*r);
  op[2]=f2bf(wv.z*xv.z*r); op[3]=f2bf(wv.w*xv.w*r);
}

// ---------------- fused attention-weight transposes (wq,wk,wv,wo) -------------
__global__ __launch_bounds__(256) void transpW4(
    const float* __restrict__ wq, const float* __restrict__ wk,
    const float* __restrict__ wv, const float* __restrict__ wo,
    short* __restrict__ wqkvT, short* __restrict__ woT)
{
  const float* in; short* out; int C;
  switch(blockIdx.z){
    case 0:  in=wq; out=wqkvT;                      C=1024; break;
    case 1:  in=wk; out=wqkvT+(size_t)1024*DM;      C=256;  break;
    case 2:  in=wv; out=wqkvT+(size_t)1280*DM;      C=256;  break;
    default: in=wo; out=woT;                        C=1024; break;
  }
  const int R=1024;
  const int r0=blockIdx.y*64, c0=blockIdx.x*32;
  if(c0>=C) return;
  __shared__ float t[64][33];
  const int tid=threadIdx.x;
  #pragma unroll
  for(int p=0;p<2;p++){
    int slot=p*256+tid;
    int ry=slot>>3, rx=slot&7;
    float4 v=*(const float4*)(in+(size_t)(r0+ry)*C+c0+rx*4);
    t[ry][rx*4+0]=v.x; t[ry][rx*4+1]=v.y; t[ry][rx*4+2]=v.z; t[ry][rx*4+3]=v.w;
  }
  __syncthreads();
  #pragma unroll
  for(int p=0;p<2;p++){
    int slot=p*256+tid;
    int cy=slot>>4, cx=slot&15;
    short4 o4;
    o4.x=f2bf(t[cx*4+0][cy]); o4.y=f2bf(t[cx*4+1][cy]);
    o4.z=f2bf(t[cx*4+2][cy]); o4.w=f2bf(t[cx*4+3][cy]);
    *(short4*)(out+(size_t)(c0+cy)*R+r0+cx*4)=o4;
  }
}

// ---------------- fused expert-weight transposes (ew1,ew2) -------------------
__global__ __launch_bounds__(256) void transpEW(
    const float* __restrict__ ew1, const float* __restrict__ ew2,
    short* __restrict__ ew1T, short* __restrict__ ew2T)
{
  const int e=blockIdx.z;
  const float* in; short* out; int R,C,bx,by;
  if(blockIdx.y<16){
    in=ew1+(size_t)e*DM*DFF; out=ew1T+(size_t)e*DFF*DM;
    R=DM; C=DFF; bx=blockIdx.x; by=blockIdx.y;
  }else{
    int idx=blockIdx.x+128*(blockIdx.y-16);
    in=ew2+(size_t)e*DFF*DM; out=ew2T+(size_t)e*DM*DFF;
    R=DFF; C=DM; bx=idx&31; by=idx>>5;
  }
  const int r0=by*64, c0=bx*32;
  __shared__ float t[64][33];
  const int tid=threadIdx.x;
  #pragma unroll
  for(int p=0;p<2;p++){
    int slot=p*256+tid;
    int ry=slot>>3, rx=slot&7;
    float4 v=*(const float4*)(in+(size_t)(r0+ry)*C+c0+rx*4);
    t[ry][rx*4+0]=v.x; t[ry][rx*4+1]=v.y; t[ry][rx*4+2]=v.z; t[ry][rx*4+3]=v.w;
  }
  __syncthreads();
  #pragma unroll
  for(int p=0;p<2;p++){
    int slot=p*256+tid;
    int cy=slot>>4, cx=slot&15;
    short4 o4;
    o4.x=f2bf(t[cx*4+0][cy]); o4.y=f2bf(t[cx*4+1][cy]);
    o4.z=f2bf(t[cx*4+2][cy]); o4.w=f2bf(t[cx*4+3][cy]);
    *(short4*)(out+(size_t)(c0+cy)*R+r0+cx*4)=o4;
  }
}

// ---------------- 128x128 tile GEMM, BK=64, swizzled LDS, single-buffer ----
template<int EPI, bool GATHER, bool MOE>
__global__ __launch_bounds__(256) void gemm128k(
    const short* __restrict__ Ab, const short* __restrict__ BTb,
    int Mfix, int N, int K, int ldb_e,
    const int* __restrict__ cnt, const int* __restrict__ off,
    const int* __restrict__ tokL,
    short* __restrict__ outb, int ldo, int ocol,
    float* __restrict__ outf, const float* __restrict__ resid,
    const float* __restrict__ biasb, int ldbias)
{
  __shared__ short As[BM*BK];
  __shared__ short Bs[BM*BK];
  const int e  = MOE ? blockIdx.z : 0;
  const int M  = MOE ? cnt[e] : Mfix;
  const int tm = blockIdx.y;
  if (tm*BM >= M) return;
  const int tn = blockIdx.x;
  const int O  = MOE ? off[e] : 0;
  const short* BT = BTb + (size_t)e * (size_t)ldb_e;

  const int tid = threadIdx.x;
  const int w = tid>>6, lane = tid&63;
  const int lr = lane&15, lg = lane>>4;
  const int wr = (w>>1)*64, wc = (w&1)*64;

  const short* pA[4]; const short* pB[4];
  #pragma unroll
  for(int i=0;i<4;i++){
    int c = i*256 + w*64 + lane;
    int cs = c ^ ((c>>3)&7);
    int r = cs>>3, k8 = (cs&7)*8;
    int grA = tm*BM + r; if (grA > M-1) grA = M-1;
    if (GATHER)      pA[i] = Ab + (size_t)tokL[O+grA]*K + k8;
    else if (MOE)    pA[i] = Ab + (size_t)(O+grA)*K + k8;
    else             pA[i] = Ab + (size_t)grA*K + k8;
    pB[i] = BT + (size_t)(tn*BM + r)*K + k8;
  }
  short* lA[4]; short* lB[4];
  #pragma unroll
  for(int i=0;i<4;i++){ lA[i]=As+i*2048+w*512; lB[i]=Bs+i*2048+w*512; }

  f32x4 acc[4][4];
  #pragma unroll
  for(int i=0;i<4;i++)
    #pragma unroll
    for(int j=0;j<4;j++) acc[i][j]=(f32x4){0.f,0.f,0.f,0.f};

  #pragma unroll
  for(int i=0;i<4;i++){ gload16(pA[i], lA[i]); gload16(pB[i], lB[i]); }

  const int koff0 = ((lg  ) ^ (lr&7))*8;
  const int koff1 = ((4+lg) ^ (lr&7))*8;

  for(int k0=0;k0<K;k0+=BK){
    __syncthreads();
    short8 af[4][2], bfr[4][2];
    #pragma unroll
    for(int mi=0;mi<4;mi++){
      const int rb=(wr+mi*16+lr)*BK;
      af[mi][0]=*(const short8*)(As+rb+koff0);
      af[mi][1]=*(const short8*)(As+rb+koff1);
    }
    #pragma unroll
    for(int ni=0;ni<4;ni++){
      const int rb=(wc+ni*16+lr)*BK;
      bfr[ni][0]=*(const short8*)(Bs+rb+koff0);
      bfr[ni][1]=*(const short8*)(Bs+rb+koff1);
    }
    __syncthreads();
    if(k0+BK<K){
      #pragma unroll
      for(int i=0;i<4;i++){ gload16(pA[i]+k0+BK, lA[i]); gload16(pB[i]+k0+BK, lB[i]); }
    }
    #pragma unroll
    for(int kk=0;kk<2;kk++)
      #pragma unroll
      for(int mi=0;mi<4;mi++)
        #pragma unroll
        for(int ni=0;ni<4;ni++)
          acc[mi][ni]=MFMA16(af[mi][kk],bfr[ni][kk],acc[mi][ni]);
  }

  #pragma unroll
  for(int mi=0;mi<4;mi++){
    const int rb = tm*BM + wr + mi*16 + 4*lg;
    #pragma unroll
    for(int ni=0;ni<4;ni++){
      const int col = tn*BM + wc + ni*16 + lr;
      f32x4 a = acc[mi][ni];
      #pragma unroll
      for(int j=0;j<4;j++){
        int r = rb + j;
        if (r < M){
          if (EPI==0){
            outb[(size_t)r*ldo + ocol + col] = f2bf(a[j]);
          } else if (EPI==1){
            size_t idx=(size_t)r*ldo + col;
            outf[idx] = resid[idx] + a[j];
          } else if (EPI==2){
            float v=a[j]+biasb[(size_t)e*ldbias+col];
            v=v/(1.f+__expf(-v));
            outb[(size_t)(O+r)*ldo + col]=f2bf(v);
          } else {
            outb[(size_t)(O+r)*ldo + col]=f2bf(a[j]+biasb[(size_t)e*ldbias+col]);
          }
        }
      }
    }
  }
}

// ---------------- fused RoPE + V-transpose ----------------
__global__ __launch_bounds__(256) void ropeV_kernel(short* __restrict__ QKV,
    short* __restrict__ VT)
{
  const int id=blockIdx.x;
  const int tid=threadIdx.x;
  __shared__ short tls[32][33];
  if(id<1024){
    const int z=id>>7, b=z>>2, kvh=z&3;
    const int s0=(id&63)*32, d0=((id>>6)&1)*32;
    const int tx=tid&31, ty=tid>>5;
    #pragma unroll
    for(int i=0;i<4;i++)
      tls[ty+i*8][tx]=QKV[(size_t)(b*2048+s0+ty+i*8)*1536+1280+kvh*64+d0+tx];
    __syncthreads();
    #pragma unroll
    for(int i=0;i<4;i++)
      VT[((size_t)(b*4+kvh)*64+d0+ty+i*8)*2048+s0+tx]=tls[tx][ty+i*8];
    return;
  }
  int t=(id-1024)*256+tid;
  if(t>=2621440) return;
  size_t addr; int s,i;
  if(t<2097152){                  // Q
    i=t&31; int rh=t>>5; int bs=rh>>4, h=rh&15; s=bs&2047;
    addr=(size_t)bs*1536+h*64+2*i;
  }else{                          // K
    t-=2097152;
    i=t&31; int rh=t>>5; int bs=rh>>2, h=rh&3; s=bs&2047;
    addr=(size_t)bs*1536+1024+h*64+2*i;
  }
  float inv=__expf(-(float)i*0.28782313662425572f); // ln(10000)/32
  float ang=(float)s*inv;
  float c=__cosf(ang), sn=__sinf(ang);
  float xe=bf2f(QKV[addr]), xo=bf2f(QKV[addr+1]);
  QKV[addr]  =f2bf(xe*c-xo*sn);
  QKV[addr+1]=f2bf(xo*c+xe*sn);
}

// ---------------- causal GQA flash attention v3 (load-balanced) ----------------
// grid (16, NQ, B); qt = (b==0) ? x : 15-x. 4 waves; wave owns 32 q rows;
// KVBLK=64. __launch_bounds__(256,4): VGPR cap 128 -> 4 blocks/CU resident.
__global__ __launch_bounds__(256,4) void attn_kernel(
    const short* __restrict__ QKV, const short* __restrict__ VT,
    short* __restrict__ O)
{
  const int b=blockIdx.z;
  const int qt = b==0 ? (int)blockIdx.x : 15-(int)blockIdx.x;
  const int h=blockIdx.y;
  const int kvh=h>>2;
  const int tid=threadIdx.x;
  const int w=tid>>6, lane=tid&63;
  const int lr=lane&15, lg=lane>>4;
  const int q0w=qt*128+w*32;

  __shared__ short Ks[64*64];
  __shared__ short Vs[64*64];
  __shared__ short Ps[4][32][72];

  short8 qf[2][2];
  #pragma unroll
  for(int qb=0;qb<2;qb++)
    #pragma unroll
    for(int ks=0;ks<2;ks++)
      qf[qb][ks]=*(const short8*)(QKV+(size_t)(b*2048+q0w+qb*16+lr)*1536+h*64+ks*32+lg*8);

  f32x4 o[2][4];
  float mj[2][4], lj[2][4];
  #pragma unroll
  for(int qb=0;qb<2;qb++)
    #pragma unroll
    for(int j=0;j<4;j++){
      mj[qb][j]=NEG_INF; lj[qb][j]=0.f;
      #pragma unroll
      for(int db=0;db<4;db++) o[qb][db]=(f32x4){0.f,0.f,0.f,0.f};
    }

  const int c1=w*64+lane;
  const int r1=c1>>3, swz=((c1&7)^(r1&7))*8;
  const short* gKb = QKV + 1024 + kvh*64 + (size_t)r1*1536 + swz;
  const short* gVb = VT + ((size_t)(b*4+kvh)*64 + r1)*2048 + swz;
  short* lK1=Ks+w*512; short* lK2=Ks+2048+w*512;
  short* lV1=Vs+w*512; short* lV2=Vs+2048+w*512;

  auto stage=[&](int kv0){
    const short* gK = gKb + (size_t)(b*2048+kv0)*1536;
    gload16(gK, lK1);
    gload16(gK + (size_t)32*1536, lK2);
    const short* gV = gVb + kv0;
    gload16(gV, lV1);
    gload16(gV + (size_t)32*2048, lV2);
  };

  const int kvend=qt*128+127;
  stage(0);
  for(int kv0=0;kv0<=kvend;kv0+=64){
    __syncthreads();
    const bool act = (kv0 <= q0w+31);
    short8 kf[4][2], vf[4][2];
    if(act){
      #pragma unroll
      for(int nb=0;nb<4;nb++)
        #pragma unroll
        for(int ks=0;ks<2;ks++)
          kf[nb][ks]=*(const short8*)(Ks+(nb*16+lr)*64+(((ks*4+lg)^(lr&7))*8));
      #pragma unroll
      for(int db=0;db<4;db++)
        #pragma unroll
        for(int ks=0;ks<2;ks++)
          vf[db][ks]=*(const short8*)(Vs+(db*16+lr)*64+(((ks*4+lg)^(lr&7))*8));
    }
    __syncthreads();
    if(kv0+64<=kvend) stage(kv0+64);
    if(!act) continue;

    f32x4 s[2][4];
    #pragma unroll
    for(int qb=0;qb<2;qb++)
      #pragma unroll
      for(int nb=0;nb<4;nb++){
        f32x4 t=(f32x4){0.f,0.f,0.f,0.f};
        t=MFMA16(qf[qb][0],kf[nb][0],t);
        t=MFMA16(qf[qb][1],kf[nb][1],t);
        s[qb][nb]=t;
      }

    const bool edge = (kv0+63 > q0w);
    float tmx[2][4];
    #pragma unroll
    for(int qb=0;qb<2;qb++)
      #pragma unroll
      for(int j=0;j<4;j++){
        float mx=NEG_INF;
        #pragma unroll
        for(int nb=0;nb<4;nb++){
          float v=s[qb][nb][j]*0.125f;
          if(edge){
            if(kv0+nb*16+lr > q0w+qb*16+4*lg+j) v=NEG_INF;
          }
          s[qb][nb][j]=v;
          mx=fmaxf(mx,v);
        }
        tmx[qb][j]=mx;
      }
    #pragma unroll
    for(int qb=0;qb<2;qb++)
      #pragma unroll
      for(int j=0;j<4;j++){
        #pragma unroll
        for(int od=1;od<16;od<<=1) tmx[qb][j]=fmaxf(tmx[qb][j],__shfl_xor(tmx[qb][j],od,64));
      }
    #pragma unroll
    for(int qb=0;qb<2;qb++)
      #pragma unroll
      for(int j=0;j<4;j++){
        float mn=fmaxf(mj[qb][j],tmx[qb][j]);
        float al=__expf(mj[qb][j]-mn);
        mj[qb][j]=mn;
        float rs=0.f;
        #pragma unroll
        for(int nb=0;nb<4;nb++){
          float pv=__expf(s[qb][nb][j]-mn);
          s[qb][nb][j]=pv;
          rs+=pv;
        }
        #pragma unroll
        for(int od=1;od<16;od<<=1) rs+=__shfl_xor(rs,od,64);
        lj[qb][j]=lj[qb][j]*al+rs;
        #pragma unroll
        for(int db=0;db<4;db++) o[qb][db][j]*=al;
      }
    #pragma unroll
    for(int qb=0;qb<2;qb++)
      #pragma unroll
      for(int nb=0;nb<4;nb++)
        #pragma unroll
        for(int j=0;j<4;j++)
          Ps[w][qb*16+4*lg+j][nb*16+lr]=f2bf(s[qb][nb][j]);
    short8 pa[2][2];
    #pragma unroll
    for(int qb=0;qb<2;qb++)
      #pragma unroll
      for(int ks=0;ks<2;ks++)
        pa[qb][ks]=*(const short8*)(&Ps[w][qb*16+lr][ks*32+lg*8]);
    #pragma unroll
    for(int qb=0;qb<2;qb++)
      #pragma unroll
      for(int db=0;db<4;db++){
        o[qb][db]=MFMA16(pa[qb][0],vf[db][0],o[qb][db]);
        o[qb][db]=MFMA16(pa[qb][1],vf[db][1],o[qb][db]);
      }
  }

  #pragma unroll
  for(int qb=0;qb<2;qb++)
    #pragma unroll
    for(int j=0;j<4;j++){
      const int qpos=q0w+qb*16+4*lg+j;
      const float inv=1.f/lj[qb][j];
      size_t base=(size_t)(b*2048+qpos)*DM+h*64;
      #pragma unroll
      for(int db=0;db<4;db++)
        O[base+db*16+lr]=f2bf(o[qb][db][j]*inv);
    }
}

// ---------------- fused RMSNorm-2 + router ----------------
__global__ __launch_bounds__(256) void rms2_router(
    const float* __restrict__ xmid, const float* __restrict__ n2w,
    const float* __restrict__ gate_w, const float* __restrict__ gate_b,
    const float* __restrict__ noise_w, const float* __restrict__ noise_b,
    const float* __restrict__ rnoise,
    short* __restrict__ h2out,
    int* __restrict__ tokE, float* __restrict__ tokS,
    int* __restrict__ cnt, float* __restrict__ imp)
{
  const int t=blockIdx.x, tid=threadIdx.x;
  const float4 xv=((const float4*)(xmid+(size_t)t*DM))[tid];
  float s=xv.x*xv.x+xv.y*xv.y+xv.z*xv.z+xv.w*xv.w;
  #pragma unroll
  for(int o=32;o;o>>=1) s+=__shfl_down(s,o,64);
  __shared__ float red[4];
  if((tid&63)==0) red[tid>>6]=s;
  __syncthreads();
  const float r=rsqrtf((red[0]+red[1]+red[2]+red[3])*(1.f/DM)+1e-8f);
  const float4 wv=((const float4*)n2w)[tid];
  float hreg[4]={wv.x*xv.x*r, wv.y*xv.y*r, wv.z*xv.z*r, wv.w*xv.w*r};
  short* op=h2out+(size_t)t*DM+tid*4;
  op[0]=f2bf(hreg[0]); op[1]=f2bf(hreg[1]);
  op[2]=f2bf(hreg[2]); op[3]=f2bf(hreg[3]);

  float acc[16];
  #pragma unroll
  for(int e=0;e<16;e++) acc[e]=0.f;
  #pragma unroll
  for(int i=0;i<4;i++){
    int d=tid*4+i;
    const float* gwr=gate_w+(size_t)d*8;
    const float* nwr=noise_w+(size_t)d*8;
    #pragma unroll
    for(int e=0;e<8;e++){ acc[e]+=hreg[i]*gwr[e]; acc[8+e]+=hreg[i]*nwr[e]; }
  }
  #pragma unroll
  for(int e=0;e<16;e++){
    #pragma unroll
    for(int o=32;o;o>>=1) acc[e]+=__shfl_down(acc[e],o,64);
  }
  __shared__ float red2[4][16];
  if((tid&63)==0){
    #pragma unroll
    for(int e=0;e<16;e++) red2[tid>>6][e]=acc[e];
  }
  __syncthreads();
  if(tid==0){
    float lgt[8];
    #pragma unroll
    for(int e=0;e<8;e++){
      float g =red2[0][e]+red2[1][e]+red2[2][e]+red2[3][e];
      float nz=red2[0][8+e]+red2[1][8+e]+red2[2][8+e]+red2[3][8+e];
      lgt[e]=g+gate_b[e]+nz+noise_b[e]+rnoise[(size_t)t*8+e];
    }
    int i1=0;
    for(int e=1;e<8;e++) if(lgt[e]>lgt[i1]) i1=e;
    int i2=(i1==0)?1:0;
    for(int e=0;e<8;e++) if(e!=i1 && lgt[e]>lgt[i2]) i2=e;
    float e2=expf(lgt[i2]-lgt[i1]);
    float den=1.f+e2;
    float s1=1.f/den, s2=e2/den;
    tokE[2*t]=i1; tokE[2*t+1]=i2;
    tokS[2*t]=s1; tokS[2*t+1]=s2;
    atomicAdd(&cnt[i1],1); atomicAdd(&cnt[i2],1);
    atomicAdd(&imp[i1],s1); atomicAdd(&imp[i2],s2);
  }
}

// ---------------- offsets scan + aux loss ----------------
__global__ void scan_aux(const int* cnt, int* off, int* cur, const float* imp, float* auxout)
{
  if(threadIdx.x==0){
    int o=0;
    for(int e=0;e<8;e++){ off[e]=o; o+=cnt[e]; cur[e]=0; }
    float u=0.125f, s=0.f;
    for(int e=0;e<8;e++) s+=u*(logf(u)-logf(imp[e]*(1.f/4096.f)+1e-8f));
    auxout[0]=s;
  }
}

// ---------------- compact token lists per expert ----------------
__global__ __launch_bounds__(256) void scatter_kernel(const int* __restrict__ tokE,
    const int* __restrict__ off, int* __restrict__ cur,
    int* __restrict__ tokL, int* __restrict__ slotOf)
{
  int t=blockIdx.x*256+threadIdx.x;
  if(t>=TKN) return;
  #pragma unroll
  for(int j=0;j<2;j++){
    int e=tokE[2*t+j];
    int idx=atomicAdd(&cur[e],1);
    int slot=off[e]+idx;
    tokL[slot]=t;
    slotOf[2*t+j]=slot;
  }
}

// ---------------- combine: dout[t] += s1*eo[slot1] + s2*eo[slot2] (eo bf16) ----
__global__ __launch_bounds__(256) void combine_kernel(const short* __restrict__ eo,
    const int* __restrict__ slotOf, const float* __restrict__ tokS,
    float* __restrict__ dout)
{
  const int t=blockIdx.x, d=threadIdx.x*4;
  const int s1=slotOf[2*t], s2=slotOf[2*t+1];
  const float w1=tokS[2*t], w2=tokS[2*t+1];
  float4 o=*(float4*)(dout+(size_t)t*DM+d);
  const short4 e1=*(const short4*)(eo+(size_t)s1*DM+d);
  const short4 e2=*(const short4*)(eo+(size_t)s2*DM+d);
  o.x+=w1*bf2f(e1.x)+w2*bf2f(e2.x);
  o.y+=w1*bf2f(e1.y)+w2*bf2f(e2.y);
  o.z+=w1*bf2f(e1.z)+w2*bf2f(e2.z);
  o.w+=w1*bf2f(e1.w)+w2*bf2f(e2.w);
  *(float4*)(dout+(size_t)t*DM+d)=o;
}

extern "C" void kernel_launch(void* const* d_in, const int* in_sizes, int n_in,
                              void* d_out, int out_size, void* d_ws, size_t ws_size,
                              hipStream_t stream)
{
  const float* x   =(const float*)d_in[0];
  const float* rn  =(const float*)d_in[1];
  const float* n1w =(const float*)d_in[2];
  const float* n2w =(const float*)d_in[3];
  const float* wq  =(const float*)d_in[4];
  const float* wk  =(const float*)d_in[5];
  const float* wv  =(const float*)d_in[6];
  const float* wo  =(const float*)d_in[7];
  const float* gw  =(const float*)d_in[8];
  const float* gb  =(const float*)d_in[9];
  const float* nw  =(const float*)d_in[10];
  const float* nb  =(const float*)d_in[11];
  const float* ew1 =(const float*)d_in[12];
  const float* eb1 =(const float*)d_in[13];
  const float* ew2 =(const float*)d_in[14];
  const float* eb2 =(const float*)d_in[15];
  float* dout=(float*)d_out;

  char* p=(char*)d_ws;
  auto take=[&](size_t n){ char* q=p; p+=(n+255)&~(size_t)255; return q; };
  short* h1    =(short*)take((size_t)TKN*DM*2);
  short* wqkvT =(short*)take((size_t)1536*DM*2);
  short* woT   =(short*)take((size_t)DM*DM*2);
  short* ew1T  =(short*)take((size_t)NE*DFF*DM*2);
  short* ew2T  =(short*)take((size_t)NE*DM*DFF*2);
  short* QKV   =(short*)take((size_t)TKN*1536*2);
  short* VTb   =(short*)take((size_t)8*64*2048*2);
  short* Ob    =(short*)take((size_t)TKN*DM*2);
  short* hh    =(short*)take((size_t)2*TKN*DFF*2);
  short* eoB   =(short*)take((size_t)2*TKN*DM*2);
  int*   tokE  =(int*)take((size_t)TKN*2*4);
  float* tokS  =(float*)take((size_t)TKN*2*4);
  int*   tokL  =(int*)take((size_t)2*TKN*4);
  int*   slotOf=(int*)take((size_t)TKN*2*4);
  int*   cnt   =(int*)take(256);
  int*   off   =cnt+8;
  int*   cur   =cnt+16;
  float* imp   =(float*)(cnt+24);

  // rms1 (+ cnt/imp zero in block 0)
  rms1_kernel<<<TKN,256,0,stream>>>(x,n1w,h1,cnt,imp);
  // fused weight transposes
  transpW4<<<dim3(32,16,4),256,0,stream>>>(wq,wk,wv,wo,wqkvT,woT);
  transpEW<<<dim3(128,32,8),256,0,stream>>>(ew1,ew2,ew1T,ew2T);

  // QKV projection: [4096][1536]
  gemm128k<0,false,false><<<dim3(12,32),256,0,stream>>>(
      h1,wqkvT,TKN,1536,DM,0, nullptr,nullptr,nullptr,
      QKV,1536,0, nullptr,nullptr, nullptr,0);
  // fused V-transpose + RoPE
  ropeV_kernel<<<11264,256,0,stream>>>(QKV,VTb);
  attn_kernel<<<dim3(16,16,2),256,0,stream>>>(QKV,VTb,Ob);
  // O projection + residual
  gemm128k<1,false,false><<<dim3(8,32),256,0,stream>>>(
      Ob,woT,TKN,DM,DM,0, nullptr,nullptr,nullptr,
      nullptr,DM,0, dout,x, nullptr,0);

  // fused rms2 + router (h1 reused as h2 buffer)
  rms2_router<<<TKN,256,0,stream>>>(dout,n2w,gw,gb,nw,nb,rn,h1,tokE,tokS,cnt,imp);
  scan_aux<<<1,64,0,stream>>>(cnt,off,cur,imp,dout+(size_t)TKN*DM);
  scatter_kernel<<<16,256,0,stream>>>(tokE,off,cur,tokL,slotOf);

  // MoE GEMM1: hh = silu(h2[tokL] @ ew1 + eb1)
  gemm128k<2,true,true><<<dim3(32,32,8),256,0,stream>>>(
      h1,ew1T,0,DFF,DM,DFF*DM, cnt,off,tokL,
      hh,DFF,0, nullptr,nullptr, eb1,DFF);
  // MoE GEMM2: eo = hh @ ew2 + eb2   (bf16 output)
  gemm128k<3,false,true><<<dim3(8,32,8),256,0,stream>>>(
      hh,ew2T,0,DM,DFF,DM*DFF, cnt,off,nullptr,
      eoB,DM,0, nullptr,nullptr, eb2,DM);
  combine_kernel<<<TKN,256,0,stream>>>(eoB,slotOf,tokS,dout);
  (void)in_sizes;(void)n_in;(void)out_size;(void)ws_size;
}

// Round 19
// 672.232 us; speedup vs baseline: 1.3009x; 1.3009x over previous
//
#include <hip/hip_runtime.h>

// DecoderLayer: rms1 -> QKV -> RoPE -> causal GQA attn -> O+resid -> rms2
// -> noisy top-2 router -> sparse MoE -> resid ; aux loss.
// B=2 S=2048 D=1024 NQ=16 NKV=4 HD=64 E=8 DFF=4096 top_k=2
// Final build = r17 (671.7 us): 13 launches, fused rms2+router, r6 GEMMs.
// r18's __launch_bounds__(256,4) on attn REVERTED (VGPR 132->64, 843MB spill).

#define TKN 4096
#define DM  1024
#define DFF 4096
#define NE  8
#define NEG_INF -3.0e38f
#define BM 128
#define BK 64

typedef __attribute__((ext_vector_type(8))) short short8;
typedef __attribute__((ext_vector_type(4))) float f32x4;

#define MFMA16(a,b,c) __builtin_amdgcn_mfma_f32_16x16x32_bf16(a,b,c,0,0,0)

__device__ __forceinline__ short f2bf(float f){
  union{float f;unsigned u;}v; v.f=f;
  unsigned r=v.u+0x7fffu+((v.u>>16)&1u);
  return (short)(r>>16);
}
__device__ __forceinline__ float bf2f(short s){
  union{unsigned u;float f;}v; v.u=((unsigned)(unsigned short)s)<<16; return v.f;
}
__device__ __forceinline__ void gload16(const short* g, short* l){
  __builtin_amdgcn_global_load_lds(
      (const __attribute__((address_space(1))) void*)g,
      (__attribute__((address_space(3))) void*)l, 16, 0, 0);
}

// ---------------- RMSNorm 1 (+ cnt/imp init in block 0), writes bf16 ----------
__global__ __launch_bounds__(256) void rms1_kernel(const float* __restrict__ x,
    const float* __restrict__ w, short* __restrict__ out,
    int* __restrict__ cnt, float* __restrict__ imp)
{
  const int row=blockIdx.x, tid=threadIdx.x;
  if(row==0 && tid<8){ cnt[tid]=0; imp[tid]=0.f; }
  const float4 xv=((const float4*)(x+(size_t)row*DM))[tid];
  float s=xv.x*xv.x+xv.y*xv.y+xv.z*xv.z+xv.w*xv.w;
  #pragma unroll
  for(int o=32;o;o>>=1) s+=__shfl_down(s,o,64);
  __shared__ float red[4];
  if((tid&63)==0) red[tid>>6]=s;
  __syncthreads();
  float r=rsqrtf((red[0]+red[1]+red[2]+red[3])*(1.f/DM)+1e-8f);
  const float4 wv=((const float4*)w)[tid];
  short* op=out+(size_t)row*DM+tid*4;
  op[0]=f2bf(wv.x*xv.x*r); op[1]=f2bf(wv.y*xv.y*r);
  op[2]=f2bf(wv.z*xv.z*r); op[3]=f2bf(wv.w*xv.w*r);
}

// ---------------- fused attention-weight transposes (wq,wk,wv,wo) -------------
__global__ __launch_bounds__(256) void transpW4(
    const float* __restrict__ wq, const float* __restrict__ wk,
    const float* __restrict__ wv, const float* __restrict__ wo,
    short* __restrict__ wqkvT, short* __restrict__ woT)
{
  const float* in; short* out; int C;
  switch(blockIdx.z){
    case 0:  in=wq; out=wqkvT;                      C=1024; break;
    case 1:  in=wk; out=wqkvT+(size_t)1024*DM;      C=256;  break;
    case 2:  in=wv; out=wqkvT+(size_t)1280*DM;      C=256;  break;
    default: in=wo; out=woT;                        C=1024; break;
  }
  const int R=1024;
  const int r0=blockIdx.y*64, c0=blockIdx.x*32;
  if(c0>=C) return;
  __shared__ float t[64][33];
  const int tid=threadIdx.x;
  #pragma unroll
  for(int p=0;p<2;p++){
    int slot=p*256+tid;
    int ry=slot>>3, rx=slot&7;
    float4 v=*(const float4*)(in+(size_t)(r0+ry)*C+c0+rx*4);
    t[ry][rx*4+0]=v.x; t[ry][rx*4+1]=v.y; t[ry][rx*4+2]=v.z; t[ry][rx*4+3]=v.w;
  }
  __syncthreads();
  #pragma unroll
  for(int p=0;p<2;p++){
    int slot=p*256+tid;
    int cy=slot>>4, cx=slot&15;
    short4 o4;
    o4.x=f2bf(t[cx*4+0][cy]); o4.y=f2bf(t[cx*4+1][cy]);
    o4.z=f2bf(t[cx*4+2][cy]); o4.w=f2bf(t[cx*4+3][cy]);
    *(short4*)(out+(size_t)(c0+cy)*R+r0+cx*4)=o4;
  }
}

// ---------------- fused expert-weight transposes (ew1,ew2) -------------------
__global__ __launch_bounds__(256) void transpEW(
    const float* __restrict__ ew1, const float* __restrict__ ew2,
    short* __restrict__ ew1T, short* __restrict__ ew2T)
{
  const int e=blockIdx.z;
  const float* in; short* out; int R,C,bx,by;
  if(blockIdx.y<16){
    in=ew1+(size_t)e*DM*DFF; out=ew1T+(size_t)e*DFF*DM;
    R=DM; C=DFF; bx=blockIdx.x; by=blockIdx.y;
  }else{
    int idx=blockIdx.x+128*(blockIdx.y-16);
    in=ew2+(size_t)e*DFF*DM; out=ew2T+(size_t)e*DM*DFF;
    R=DFF; C=DM; bx=idx&31; by=idx>>5;
  }
  const int r0=by*64, c0=bx*32;
  __shared__ float t[64][33];
  const int tid=threadIdx.x;
  #pragma unroll
  for(int p=0;p<2;p++){
    int slot=p*256+tid;
    int ry=slot>>3, rx=slot&7;
    float4 v=*(const float4*)(in+(size_t)(r0+ry)*C+c0+rx*4);
    t[ry][rx*4+0]=v.x; t[ry][rx*4+1]=v.y; t[ry][rx*4+2]=v.z; t[ry][rx*4+3]=v.w;
  }
  __syncthreads();
  #pragma unroll
  for(int p=0;p<2;p++){
    int slot=p*256+tid;
    int cy=slot>>4, cx=slot&15;
    short4 o4;
    o4.x=f2bf(t[cx*4+0][cy]); o4.y=f2bf(t[cx*4+1][cy]);
    o4.z=f2bf(t[cx*4+2][cy]); o4.w=f2bf(t[cx*4+3][cy]);
    *(short4*)(out+(size_t)(c0+cy)*R+r0+cx*4)=o4;
  }
}

// ---------------- 128x128 tile GEMM, BK=64, swizzled LDS, single-buffer ----
template<int EPI, bool GATHER, bool MOE>
__global__ __launch_bounds__(256) void gemm128k(
    const short* __restrict__ Ab, const short* __restrict__ BTb,
    int Mfix, int N, int K, int ldb_e,
    const int* __restrict__ cnt, const int* __restrict__ off,
    const int* __restrict__ tokL,
    short* __restrict__ outb, int ldo, int ocol,
    float* __restrict__ outf, const float* __restrict__ resid,
    const float* __restrict__ biasb, int ldbias)
{
  __shared__ short As[BM*BK];
  __shared__ short Bs[BM*BK];
  const int e  = MOE ? blockIdx.z : 0;
  const int M  = MOE ? cnt[e] : Mfix;
  const int tm = blockIdx.y;
  if (tm*BM >= M) return;
  const int tn = blockIdx.x;
  const int O  = MOE ? off[e] : 0;
  const short* BT = BTb + (size_t)e * (size_t)ldb_e;

  const int tid = threadIdx.x;
  const int w = tid>>6, lane = tid&63;
  const int lr = lane&15, lg = lane>>4;
  const int wr = (w>>1)*64, wc = (w&1)*64;

  const short* pA[4]; const short* pB[4];
  #pragma unroll
  for(int i=0;i<4;i++){
    int c = i*256 + w*64 + lane;
    int cs = c ^ ((c>>3)&7);
    int r = cs>>3, k8 = (cs&7)*8;
    int grA = tm*BM + r; if (grA > M-1) grA = M-1;
    if (GATHER)      pA[i] = Ab + (size_t)tokL[O+grA]*K + k8;
    else if (MOE)    pA[i] = Ab + (size_t)(O+grA)*K + k8;
    else             pA[i] = Ab + (size_t)grA*K + k8;
    pB[i] = BT + (size_t)(tn*BM + r)*K + k8;
  }
  short* lA[4]; short* lB[4];
  #pragma unroll
  for(int i=0;i<4;i++){ lA[i]=As+i*2048+w*512; lB[i]=Bs+i*2048+w*512; }

  f32x4 acc[4][4];
  #pragma unroll
  for(int i=0;i<4;i++)
    #pragma unroll
    for(int j=0;j<4;j++) acc[i][j]=(f32x4){0.f,0.f,0.f,0.f};

  #pragma unroll
  for(int i=0;i<4;i++){ gload16(pA[i], lA[i]); gload16(pB[i], lB[i]); }

  const int koff0 = ((lg  ) ^ (lr&7))*8;
  const int koff1 = ((4+lg) ^ (lr&7))*8;

  for(int k0=0;k0<K;k0+=BK){
    __syncthreads();
    short8 af[4][2], bfr[4][2];
    #pragma unroll
    for(int mi=0;mi<4;mi++){
      const int rb=(wr+mi*16+lr)*BK;
      af[mi][0]=*(const short8*)(As+rb+koff0);
      af[mi][1]=*(const short8*)(As+rb+koff1);
    }
    #pragma unroll
    for(int ni=0;ni<4;ni++){
      const int rb=(wc+ni*16+lr)*BK;
      bfr[ni][0]=*(const short8*)(Bs+rb+koff0);
      bfr[ni][1]=*(const short8*)(Bs+rb+koff1);
    }
    __syncthreads();
    if(k0+BK<K){
      #pragma unroll
      for(int i=0;i<4;i++){ gload16(pA[i]+k0+BK, lA[i]); gload16(pB[i]+k0+BK, lB[i]); }
    }
    #pragma unroll
    for(int kk=0;kk<2;kk++)
      #pragma unroll
      for(int mi=0;mi<4;mi++)
        #pragma unroll
        for(int ni=0;ni<4;ni++)
          acc[mi][ni]=MFMA16(af[mi][kk],bfr[ni][kk],acc[mi][ni]);
  }

  #pragma unroll
  for(int mi=0;mi<4;mi++){
    const int rb = tm*BM + wr + mi*16 + 4*lg;
    #pragma unroll
    for(int ni=0;ni<4;ni++){
      const int col = tn*BM + wc + ni*16 + lr;
      f32x4 a = acc[mi][ni];
      #pragma unroll
      for(int j=0;j<4;j++){
        int r = rb + j;
        if (r < M){
          if (EPI==0){
            outb[(size_t)r*ldo + ocol + col] = f2bf(a[j]);
          } else if (EPI==1){
            size_t idx=(size_t)r*ldo + col;
            outf[idx] = resid[idx] + a[j];
          } else if (EPI==2){
            float v=a[j]+biasb[(size_t)e*ldbias+col];
            v=v/(1.f+__expf(-v));
            outb[(size_t)(O+r)*ldo + col]=f2bf(v);
          } else {
            outb[(size_t)(O+r)*ldo + col]=f2bf(a[j]+biasb[(size_t)e*ldbias+col]);
          }
        }
      }
    }
  }
}

// ---------------- fused RoPE + V-transpose ----------------
__global__ __launch_bounds__(256) void ropeV_kernel(short* __restrict__ QKV,
    short* __restrict__ VT)
{
  const int id=blockIdx.x;
  const int tid=threadIdx.x;
  __shared__ short tls[32][33];
  if(id<1024){
    const int z=id>>7, b=z>>2, kvh=z&3;
    const int s0=(id&63)*32, d0=((id>>6)&1)*32;
    const int tx=tid&31, ty=tid>>5;
    #pragma unroll
    for(int i=0;i<4;i++)
      tls[ty+i*8][tx]=QKV[(size_t)(b*2048+s0+ty+i*8)*1536+1280+kvh*64+d0+tx];
    __syncthreads();
    #pragma unroll
    for(int i=0;i<4;i++)
      VT[((size_t)(b*4+kvh)*64+d0+ty+i*8)*2048+s0+tx]=tls[tx][ty+i*8];
    return;
  }
  int t=(id-1024)*256+tid;
  if(t>=2621440) return;
  size_t addr; int s,i;
  if(t<2097152){                  // Q
    i=t&31; int rh=t>>5; int bs=rh>>4, h=rh&15; s=bs&2047;
    addr=(size_t)bs*1536+h*64+2*i;
  }else{                          // K
    t-=2097152;
    i=t&31; int rh=t>>5; int bs=rh>>2, h=rh&3; s=bs&2047;
    addr=(size_t)bs*1536+1024+h*64+2*i;
  }
  float inv=__expf(-(float)i*0.28782313662425572f); // ln(10000)/32
  float ang=(float)s*inv;
  float c=__cosf(ang), sn=__sinf(ang);
  float xe=bf2f(QKV[addr]), xo=bf2f(QKV[addr+1]);
  QKV[addr]  =f2bf(xe*c-xo*sn);
  QKV[addr+1]=f2bf(xo*c+xe*sn);
}

// ---------------- causal GQA flash attention v3 (load-balanced) ----------------
// grid (16, NQ, B); qt = (b==0) ? x : 15-x. 4 waves; wave owns 32 q rows;
// KVBLK=64. Natural VGPR allocation (132) — do NOT cap (r18 spill lesson).
__global__ __launch_bounds__(256) void attn_kernel(
    const short* __restrict__ QKV, const short* __restrict__ VT,
    short* __restrict__ O)
{
  const int b=blockIdx.z;
  const int qt = b==0 ? (int)blockIdx.x : 15-(int)blockIdx.x;
  const int h=blockIdx.y;
  const int kvh=h>>2;
  const int tid=threadIdx.x;
  const int w=tid>>6, lane=tid&63;
  const int lr=lane&15, lg=lane>>4;
  const int q0w=qt*128+w*32;

  __shared__ short Ks[64*64];
  __shared__ short Vs[64*64];
  __shared__ short Ps[4][32][72];

  short8 qf[2][2];
  #pragma unroll
  for(int qb=0;qb<2;qb++)
    #pragma unroll
    for(int ks=0;ks<2;ks++)
      qf[qb][ks]=*(const short8*)(QKV+(size_t)(b*2048+q0w+qb*16+lr)*1536+h*64+ks*32+lg*8);

  f32x4 o[2][4];
  float mj[2][4], lj[2][4];
  #pragma unroll
  for(int qb=0;qb<2;qb++)
    #pragma unroll
    for(int j=0;j<4;j++){
      mj[qb][j]=NEG_INF; lj[qb][j]=0.f;
      #pragma unroll
      for(int db=0;db<4;db++) o[qb][db]=(f32x4){0.f,0.f,0.f,0.f};
    }

  const int c1=w*64+lane;
  const int r1=c1>>3, swz=((c1&7)^(r1&7))*8;
  const short* gKb = QKV + 1024 + kvh*64 + (size_t)r1*1536 + swz;
  const short* gVb = VT + ((size_t)(b*4+kvh)*64 + r1)*2048 + swz;
  short* lK1=Ks+w*512; short* lK2=Ks+2048+w*512;
  short* lV1=Vs+w*512; short* lV2=Vs+2048+w*512;

  auto stage=[&](int kv0){
    const short* gK = gKb + (size_t)(b*2048+kv0)*1536;
    gload16(gK, lK1);
    gload16(gK + (size_t)32*1536, lK2);
    const short* gV = gVb + kv0;
    gload16(gV, lV1);
    gload16(gV + (size_t)32*2048, lV2);
  };

  const int kvend=qt*128+127;
  stage(0);
  for(int kv0=0;kv0<=kvend;kv0+=64){
    __syncthreads();
    const bool act = (kv0 <= q0w+31);
    short8 kf[4][2], vf[4][2];
    if(act){
      #pragma unroll
      for(int nb=0;nb<4;nb++)
        #pragma unroll
        for(int ks=0;ks<2;ks++)
          kf[nb][ks]=*(const short8*)(Ks+(nb*16+lr)*64+(((ks*4+lg)^(lr&7))*8));
      #pragma unroll
      for(int db=0;db<4;db++)
        #pragma unroll
        for(int ks=0;ks<2;ks++)
          vf[db][ks]=*(const short8*)(Vs+(db*16+lr)*64+(((ks*4+lg)^(lr&7))*8));
    }
    __syncthreads();
    if(kv0+64<=kvend) stage(kv0+64);
    if(!act) continue;

    f32x4 s[2][4];
    #pragma unroll
    for(int qb=0;qb<2;qb++)
      #pragma unroll
      for(int nb=0;nb<4;nb++){
        f32x4 t=(f32x4){0.f,0.f,0.f,0.f};
        t=MFMA16(qf[qb][0],kf[nb][0],t);
        t=MFMA16(qf[qb][1],kf[nb][1],t);
        s[qb][nb]=t;
      }

    const bool edge = (kv0+63 > q0w);
    float tmx[2][4];
    #pragma unroll
    for(int qb=0;qb<2;qb++)
      #pragma unroll
      for(int j=0;j<4;j++){
        float mx=NEG_INF;
        #pragma unroll
        for(int nb=0;nb<4;nb++){
          float v=s[qb][nb][j]*0.125f;
          if(edge){
            if(kv0+nb*16+lr > q0w+qb*16+4*lg+j) v=NEG_INF;
          }
          s[qb][nb][j]=v;
          mx=fmaxf(mx,v);
        }
        tmx[qb][j]=mx;
      }
    #pragma unroll
    for(int qb=0;qb<2;qb++)
      #pragma unroll
      for(int j=0;j<4;j++){
        #pragma unroll
        for(int od=1;od<16;od<<=1) tmx[qb][j]=fmaxf(tmx[qb][j],__shfl_xor(tmx[qb][j],od,64));
      }
    #pragma unroll
    for(int qb=0;qb<2;qb++)
      #pragma unroll
      for(int j=0;j<4;j++){
        float mn=fmaxf(mj[qb][j],tmx[qb][j]);
        float al=__expf(mj[qb][j]-mn);
        mj[qb][j]=mn;
        float rs=0.f;
        #pragma unroll
        for(int nb=0;nb<4;nb++){
          float pv=__expf(s[qb][nb][j]-mn);
          s[qb][nb][j]=pv;
          rs+=pv;
        }
        #pragma unroll
        for(int od=1;od<16;od<<=1) rs+=__shfl_xor(rs,od,64);
        lj[qb][j]=lj[qb][j]*al+rs;
        #pragma unroll
        for(int db=0;db<4;db++) o[qb][db][j]*=al;
      }
    #pragma unroll
    for(int qb=0;qb<2;qb++)
      #pragma unroll
      for(int nb=0;nb<4;nb++)
        #pragma unroll
        for(int j=0;j<4;j++)
          Ps[w][qb*16+4*lg+j][nb*16+lr]=f2bf(s[qb][nb][j]);
    short8 pa[2][2];
    #pragma unroll
    for(int qb=0;qb<2;qb++)
      #pragma unroll
      for(int ks=0;ks<2;ks++)
        pa[qb][ks]=*(const short8*)(&Ps[w][qb*16+lr][ks*32+lg*8]);
    #pragma unroll
    for(int qb=0;qb<2;qb++)
      #pragma unroll
      for(int db=0;db<4;db++){
        o[qb][db]=MFMA16(pa[qb][0],vf[db][0],o[qb][db]);
        o[qb][db]=MFMA16(pa[qb][1],vf[db][1],o[qb][db]);
      }
  }

  #pragma unroll
  for(int qb=0;qb<2;qb++)
    #pragma unroll
    for(int j=0;j<4;j++){
      const int qpos=q0w+qb*16+4*lg+j;
      const float inv=1.f/lj[qb][j];
      size_t base=(size_t)(b*2048+qpos)*DM+h*64;
      #pragma unroll
      for(int db=0;db<4;db++)
        O[base+db*16+lr]=f2bf(o[qb][db][j]*inv);
    }
}

// ---------------- fused RMSNorm-2 + router ----------------
__global__ __launch_bounds__(256) void rms2_router(
    const float* __restrict__ xmid, const float* __restrict__ n2w,
    const float* __restrict__ gate_w, const float* __restrict__ gate_b,
    const float* __restrict__ noise_w, const float* __restrict__ noise_b,
    const float* __restrict__ rnoise,
    short* __restrict__ h2out,
    int* __restrict__ tokE, float* __restrict__ tokS,
    int* __restrict__ cnt, float* __restrict__ imp)
{
  const int t=blockIdx.x, tid=threadIdx.x;
  const float4 xv=((const float4*)(xmid+(size_t)t*DM))[tid];
  float s=xv.x*xv.x+xv.y*xv.y+xv.z*xv.z+xv.w*xv.w;
  #pragma unroll
  for(int o=32;o;o>>=1) s+=__shfl_down(s,o,64);
  __shared__ float red[4];
  if((tid&63)==0) red[tid>>6]=s;
  __syncthreads();
  const float r=rsqrtf((red[0]+red[1]+red[2]+red[3])*(1.f/DM)+1e-8f);
  const float4 wv=((const float4*)n2w)[tid];
  float hreg[4]={wv.x*xv.x*r, wv.y*xv.y*r, wv.z*xv.z*r, wv.w*xv.w*r};
  short* op=h2out+(size_t)t*DM+tid*4;
  op[0]=f2bf(hreg[0]); op[1]=f2bf(hreg[1]);
  op[2]=f2bf(hreg[2]); op[3]=f2bf(hreg[3]);

  float acc[16];
  #pragma unroll
  for(int e=0;e<16;e++) acc[e]=0.f;
  #pragma unroll
  for(int i=0;i<4;i++){
    int d=tid*4+i;
    const float* gwr=gate_w+(size_t)d*8;
    const float* nwr=noise_w+(size_t)d*8;
    #pragma unroll
    for(int e=0;e<8;e++){ acc[e]+=hreg[i]*gwr[e]; acc[8+e]+=hreg[i]*nwr[e]; }
  }
  #pragma unroll
  for(int e=0;e<16;e++){
    #pragma unroll
    for(int o=32;o;o>>=1) acc[e]+=__shfl_down(acc[e],o,64);
  }
  __shared__ float red2[4][16];
  if((tid&63)==0){
    #pragma unroll
    for(int e=0;e<16;e++) red2[tid>>6][e]=acc[e];
  }
  __syncthreads();
  if(tid==0){
    float lgt[8];
    #pragma unroll
    for(int e=0;e<8;e++){
      float g =red2[0][e]+red2[1][e]+red2[2][e]+red2[3][e];
      float nz=red2[0][8+e]+red2[1][8+e]+red2[2][8+e]+red2[3][8+e];
      lgt[e]=g+gate_b[e]+nz+noise_b[e]+rnoise[(size_t)t*8+e];
    }
    int i1=0;
    for(int e=1;e<8;e++) if(lgt[e]>lgt[i1]) i1=e;
    int i2=(i1==0)?1:0;
    for(int e=0;e<8;e++) if(e!=i1 && lgt[e]>lgt[i2]) i2=e;
    float e2=expf(lgt[i2]-lgt[i1]);
    float den=1.f+e2;
    float s1=1.f/den, s2=e2/den;
    tokE[2*t]=i1; tokE[2*t+1]=i2;
    tokS[2*t]=s1; tokS[2*t+1]=s2;
    atomicAdd(&cnt[i1],1); atomicAdd(&cnt[i2],1);
    atomicAdd(&imp[i1],s1); atomicAdd(&imp[i2],s2);
  }
}

// ---------------- offsets scan + aux loss ----------------
__global__ void scan_aux(const int* cnt, int* off, int* cur, const float* imp, float* auxout)
{
  if(threadIdx.x==0){
    int o=0;
    for(int e=0;e<8;e++){ off[e]=o; o+=cnt[e]; cur[e]=0; }
    float u=0.125f, s=0.f;
    for(int e=0;e<8;e++) s+=u*(logf(u)-logf(imp[e]*(1.f/4096.f)+1e-8f));
    auxout[0]=s;
  }
}

// ---------------- compact token lists per expert ----------------
__global__ __launch_bounds__(256) void scatter_kernel(const int* __restrict__ tokE,
    const int* __restrict__ off, int* __restrict__ cur,
    int* __restrict__ tokL, int* __restrict__ slotOf)
{
  int t=blockIdx.x*256+threadIdx.x;
  if(t>=TKN) return;
  #pragma unroll
  for(int j=0;j<2;j++){
    int e=tokE[2*t+j];
    int idx=atomicAdd(&cur[e],1);
    int slot=off[e]+idx;
    tokL[slot]=t;
    slotOf[2*t+j]=slot;
  }
}

// ---------------- combine: dout[t] += s1*eo[slot1] + s2*eo[slot2] (eo bf16) ----
__global__ __launch_bounds__(256) void combine_kernel(const short* __restrict__ eo,
    const int* __restrict__ slotOf, const float* __restrict__ tokS,
    float* __restrict__ dout)
{
  const int t=blockIdx.x, d=threadIdx.x*4;
  const int s1=slotOf[2*t], s2=slotOf[2*t+1];
  const float w1=tokS[2*t], w2=tokS[2*t+1];
  float4 o=*(float4*)(dout+(size_t)t*DM+d);
  const short4 e1=*(const short4*)(eo+(size_t)s1*DM+d);
  const short4 e2=*(const short4*)(eo+(size_t)s2*DM+d);
  o.x+=w1*bf2f(e1.x)+w2*bf2f(e2.x);
  o.y+=w1*bf2f(e1.y)+w2*bf2f(e2.y);
  o.z+=w1*bf2f(e1.z)+w2*bf2f(e2.z);
  o.w+=w1*bf2f(e1.w)+w2*bf2f(e2.w);
  *(float4*)(dout+(size_t)t*DM+d)=o;
}

extern "C" void kernel_launch(void* const* d_in, const int* in_sizes, int n_in,
                              void* d_out, int out_size, void* d_ws, size_t ws_size,
                              hipStream_t stream)
{
  const float* x   =(const float*)d_in[0];
  const float* rn  =(const float*)d_in[1];
  const float* n1w =(const float*)d_in[2];
  const float* n2w =(const float*)d_in[3];
  const float* wq  =(const float*)d_in[4];
  const float* wk  =(const float*)d_in[5];
  const float* wv  =(const float*)d_in[6];
  const float* wo  =(const float*)d_in[7];
  const float* gw  =(const float*)d_in[8];
  const float* gb  =(const float*)d_in[9];
  const float* nw  =(const float*)d_in[10];
  const float* nb  =(const float*)d_in[11];
  const float* ew1 =(const float*)d_in[12];
  const float* eb1 =(const float*)d_in[13];
  const float* ew2 =(const float*)d_in[14];
  const float* eb2 =(const float*)d_in[15];
  float* dout=(float*)d_out;

  char* p=(char*)d_ws;
  auto take=[&](size_t n){ char* q=p; p+=(n+255)&~(size_t)255; return q; };
  short* h1    =(short*)take((size_t)TKN*DM*2);
  short* wqkvT =(short*)take((size_t)1536*DM*2);
  short* woT   =(short*)take((size_t)DM*DM*2);
  short* ew1T  =(short*)take((size_t)NE*DFF*DM*2);
  short* ew2T  =(short*)take((size_t)NE*DM*DFF*2);
  short* QKV   =(short*)take((size_t)TKN*1536*2);
  short* VTb   =(short*)take((size_t)8*64*2048*2);
  short* Ob    =(short*)take((size_t)TKN*DM*2);
  short* hh    =(short*)take((size_t)2*TKN*DFF*2);
  short* eoB   =(short*)take((size_t)2*TKN*DM*2);
  int*   tokE  =(int*)take((size_t)TKN*2*4);
  float* tokS  =(float*)take((size_t)TKN*2*4);
  int*   tokL  =(int*)take((size_t)2*TKN*4);
  int*   slotOf=(int*)take((size_t)TKN*2*4);
  int*   cnt   =(int*)take(256);
  int*   off   =cnt+8;
  int*   cur   =cnt+16;
  float* imp   =(float*)(cnt+24);

  // rms1 (+ cnt/imp zero in block 0)
  rms1_kernel<<<TKN,256,0,stream>>>(x,n1w,h1,cnt,imp);
  // fused weight transposes
  transpW4<<<dim3(32,16,4),256,0,stream>>>(wq,wk,wv,wo,wqkvT,woT);
  transpEW<<<dim3(128,32,8),256,0,stream>>>(ew1,ew2,ew1T,ew2T);

  // QKV projection: [4096][1536]
  gemm128k<0,false,false><<<dim3(12,32),256,0,stream>>>(
      h1,wqkvT,TKN,1536,DM,0, nullptr,nullptr,nullptr,
      QKV,1536,0, nullptr,nullptr, nullptr,0);
  // fused V-transpose + RoPE
  ropeV_kernel<<<11264,256,0,stream>>>(QKV,VTb);
  attn_kernel<<<dim3(16,16,2),256,0,stream>>>(QKV,VTb,Ob);
  // O projection + residual
  gemm128k<1,false,false><<<dim3(8,32),256,0,stream>>>(
      Ob,woT,TKN,DM,DM,0, nullptr,nullptr,nullptr,
      nullptr,DM,0, dout,x, nullptr,0);

  // fused rms2 + router (h1 reused as h2 buffer)
  rms2_router<<<TKN,256,0,stream>>>(dout,n2w,gw,gb,nw,nb,rn,h1,tokE,tokS,cnt,imp);
  scan_aux<<<1,64,0,stream>>>(cnt,off,cur,imp,dout+(size_t)TKN*DM);
  scatter_kernel<<<16,256,0,stream>>>(tokE,off,cur,tokL,slotOf);

  // MoE GEMM1: hh = silu(h2[tokL] @ ew1 + eb1)
  gemm128k<2,true,true><<<dim3(32,32,8),256,0,stream>>>(
      h1,ew1T,0,DFF,DM,DFF*DM, cnt,off,tokL,
      hh,DFF,0, nullptr,nullptr, eb1,DFF);
  // MoE GEMM2: eo = hh @ ew2 + eb2   (bf16 output)
  gemm128k<3,false,true><<<dim3(8,32,8),256,0,stream>>>(
      hh,ew2T,0,DM,DFF,DM*DFF, cnt,off,nullptr,
      eoB,DM,0, nullptr,nullptr, eb2,DM);
  combine_kernel<<<TKN,256,0,stream>>>(eoB,slotOf,tokS,dout);
  (void)in_sizes;(void)n_in;(void)out_size;(void)ws_size;
}

// Round 20
// 562.283 us; speedup vs baseline: 1.5553x; 1.1955x over previous
//
#include <hip/hip_runtime.h>

// DecoderLayer: rms1 -> QKV -> RoPE -> causal GQA attn -> O+resid -> rms2
// -> noisy top-2 router -> sparse MoE -> resid ; aux loss.
// B=2 S=2048 D=1024 NQ=16 NKV=4 HD=64 E=8 DFF=4096 top_k=2
// r19: 672 us. r20: router atomics removed (16384 same-line L2 atomics were
// ~130 us); deterministic single-block router_scan replaces scan_aux+scatter.

#define TKN 4096
#define DM  1024
#define DFF 4096
#define NE  8
#define NEG_INF -3.0e38f
#define BM 128
#define BK 64

typedef __attribute__((ext_vector_type(8))) short short8;
typedef __attribute__((ext_vector_type(4))) float f32x4;

#define MFMA16(a,b,c) __builtin_amdgcn_mfma_f32_16x16x32_bf16(a,b,c,0,0,0)

__device__ __forceinline__ short f2bf(float f){
  union{float f;unsigned u;}v; v.f=f;
  unsigned r=v.u+0x7fffu+((v.u>>16)&1u);
  return (short)(r>>16);
}
__device__ __forceinline__ float bf2f(short s){
  union{unsigned u;float f;}v; v.u=((unsigned)(unsigned short)s)<<16; return v.f;
}
__device__ __forceinline__ void gload16(const short* g, short* l){
  __builtin_amdgcn_global_load_lds(
      (const __attribute__((address_space(1))) void*)g,
      (__attribute__((address_space(3))) void*)l, 16, 0, 0);
}

// ---------------- RMSNorm 1, writes bf16 ----------
__global__ __launch_bounds__(256) void rms1_kernel(const float* __restrict__ x,
    const float* __restrict__ w, short* __restrict__ out)
{
  const int row=blockIdx.x, tid=threadIdx.x;
  const float4 xv=((const float4*)(x+(size_t)row*DM))[tid];
  float s=xv.x*xv.x+xv.y*xv.y+xv.z*xv.z+xv.w*xv.w;
  #pragma unroll
  for(int o=32;o;o>>=1) s+=__shfl_down(s,o,64);
  __shared__ float red[4];
  if((tid&63)==0) red[tid>>6]=s;
  __syncthreads();
  float r=rsqrtf((red[0]+red[1]+red[2]+red[3])*(1.f/DM)+1e-8f);
  const float4 wv=((const float4*)w)[tid];
  short* op=out+(size_t)row*DM+tid*4;
  op[0]=f2bf(wv.x*xv.x*r); op[1]=f2bf(wv.y*xv.y*r);
  op[2]=f2bf(wv.z*xv.z*r); op[3]=f2bf(wv.w*xv.w*r);
}

// ---------------- fused attention-weight transposes (wq,wk,wv,wo) -------------
__global__ __launch_bounds__(256) void transpW4(
    const float* __restrict__ wq, const float* __restrict__ wk,
    const float* __restrict__ wv, const float* __restrict__ wo,
    short* __restrict__ wqkvT, short* __restrict__ woT)
{
  const float* in; short* out; int C;
  switch(blockIdx.z){
    case 0:  in=wq; out=wqkvT;                      C=1024; break;
    case 1:  in=wk; out=wqkvT+(size_t)1024*DM;      C=256;  break;
    case 2:  in=wv; out=wqkvT+(size_t)1280*DM;      C=256;  break;
    default: in=wo; out=woT;                        C=1024; break;
  }
  const int R=1024;
  const int r0=blockIdx.y*64, c0=blockIdx.x*32;
  if(c0>=C) return;
  __shared__ float t[64][33];
  const int tid=threadIdx.x;
  #pragma unroll
  for(int p=0;p<2;p++){
    int slot=p*256+tid;
    int ry=slot>>3, rx=slot&7;
    float4 v=*(const float4*)(in+(size_t)(r0+ry)*C+c0+rx*4);
    t[ry][rx*4+0]=v.x; t[ry][rx*4+1]=v.y; t[ry][rx*4+2]=v.z; t[ry][rx*4+3]=v.w;
  }
  __syncthreads();
  #pragma unroll
  for(int p=0;p<2;p++){
    int slot=p*256+tid;
    int cy=slot>>4, cx=slot&15;
    short4 o4;
    o4.x=f2bf(t[cx*4+0][cy]); o4.y=f2bf(t[cx*4+1][cy]);
    o4.z=f2bf(t[cx*4+2][cy]); o4.w=f2bf(t[cx*4+3][cy]);
    *(short4*)(out+(size_t)(c0+cy)*R+r0+cx*4)=o4;
  }
}

// ---------------- fused expert-weight transposes (ew1,ew2) -------------------
__global__ __launch_bounds__(256) void transpEW(
    const float* __restrict__ ew1, const float* __restrict__ ew2,
    short* __restrict__ ew1T, short* __restrict__ ew2T)
{
  const int e=blockIdx.z;
  const float* in; short* out; int R,C,bx,by;
  if(blockIdx.y<16){
    in=ew1+(size_t)e*DM*DFF; out=ew1T+(size_t)e*DFF*DM;
    R=DM; C=DFF; bx=blockIdx.x; by=blockIdx.y;
  }else{
    int idx=blockIdx.x+128*(blockIdx.y-16);
    in=ew2+(size_t)e*DFF*DM; out=ew2T+(size_t)e*DM*DFF;
    R=DFF; C=DM; bx=idx&31; by=idx>>5;
  }
  const int r0=by*64, c0=bx*32;
  __shared__ float t[64][33];
  const int tid=threadIdx.x;
  #pragma unroll
  for(int p=0;p<2;p++){
    int slot=p*256+tid;
    int ry=slot>>3, rx=slot&7;
    float4 v=*(const float4*)(in+(size_t)(r0+ry)*C+c0+rx*4);
    t[ry][rx*4+0]=v.x; t[ry][rx*4+1]=v.y; t[ry][rx*4+2]=v.z; t[ry][rx*4+3]=v.w;
  }
  __syncthreads();
  #pragma unroll
  for(int p=0;p<2;p++){
    int slot=p*256+tid;
    int cy=slot>>4, cx=slot&15;
    short4 o4;
    o4.x=f2bf(t[cx*4+0][cy]); o4.y=f2bf(t[cx*4+1][cy]);
    o4.z=f2bf(t[cx*4+2][cy]); o4.w=f2bf(t[cx*4+3][cy]);
    *(short4*)(out+(size_t)(c0+cy)*R+r0+cx*4)=o4;
  }
}

// ---------------- 128x128 tile GEMM, BK=64, swizzled LDS, single-buffer ----
template<int EPI, bool GATHER, bool MOE>
__global__ __launch_bounds__(256) void gemm128k(
    const short* __restrict__ Ab, const short* __restrict__ BTb,
    int Mfix, int N, int K, int ldb_e,
    const int* __restrict__ cnt, const int* __restrict__ off,
    const int* __restrict__ tokL,
    short* __restrict__ outb, int ldo, int ocol,
    float* __restrict__ outf, const float* __restrict__ resid,
    const float* __restrict__ biasb, int ldbias)
{
  __shared__ short As[BM*BK];
  __shared__ short Bs[BM*BK];
  const int e  = MOE ? blockIdx.z : 0;
  const int M  = MOE ? cnt[e] : Mfix;
  const int tm = blockIdx.y;
  if (tm*BM >= M) return;
  const int tn = blockIdx.x;
  const int O  = MOE ? off[e] : 0;
  const short* BT = BTb + (size_t)e * (size_t)ldb_e;

  const int tid = threadIdx.x;
  const int w = tid>>6, lane = tid&63;
  const int lr = lane&15, lg = lane>>4;
  const int wr = (w>>1)*64, wc = (w&1)*64;

  const short* pA[4]; const short* pB[4];
  #pragma unroll
  for(int i=0;i<4;i++){
    int c = i*256 + w*64 + lane;
    int cs = c ^ ((c>>3)&7);
    int r = cs>>3, k8 = (cs&7)*8;
    int grA = tm*BM + r; if (grA > M-1) grA = M-1;
    if (GATHER)      pA[i] = Ab + (size_t)tokL[O+grA]*K + k8;
    else if (MOE)    pA[i] = Ab + (size_t)(O+grA)*K + k8;
    else             pA[i] = Ab + (size_t)grA*K + k8;
    pB[i] = BT + (size_t)(tn*BM + r)*K + k8;
  }
  short* lA[4]; short* lB[4];
  #pragma unroll
  for(int i=0;i<4;i++){ lA[i]=As+i*2048+w*512; lB[i]=Bs+i*2048+w*512; }

  f32x4 acc[4][4];
  #pragma unroll
  for(int i=0;i<4;i++)
    #pragma unroll
    for(int j=0;j<4;j++) acc[i][j]=(f32x4){0.f,0.f,0.f,0.f};

  #pragma unroll
  for(int i=0;i<4;i++){ gload16(pA[i], lA[i]); gload16(pB[i], lB[i]); }

  const int koff0 = ((lg  ) ^ (lr&7))*8;
  const int koff1 = ((4+lg) ^ (lr&7))*8;

  for(int k0=0;k0<K;k0+=BK){
    __syncthreads();
    short8 af[4][2], bfr[4][2];
    #pragma unroll
    for(int mi=0;mi<4;mi++){
      const int rb=(wr+mi*16+lr)*BK;
      af[mi][0]=*(const short8*)(As+rb+koff0);
      af[mi][1]=*(const short8*)(As+rb+koff1);
    }
    #pragma unroll
    for(int ni=0;ni<4;ni++){
      const int rb=(wc+ni*16+lr)*BK;
      bfr[ni][0]=*(const short8*)(Bs+rb+koff0);
      bfr[ni][1]=*(const short8*)(Bs+rb+koff1);
    }
    __syncthreads();
    if(k0+BK<K){
      #pragma unroll
      for(int i=0;i<4;i++){ gload16(pA[i]+k0+BK, lA[i]); gload16(pB[i]+k0+BK, lB[i]); }
    }
    #pragma unroll
    for(int kk=0;kk<2;kk++)
      #pragma unroll
      for(int mi=0;mi<4;mi++)
        #pragma unroll
        for(int ni=0;ni<4;ni++)
          acc[mi][ni]=MFMA16(af[mi][kk],bfr[ni][kk],acc[mi][ni]);
  }

  #pragma unroll
  for(int mi=0;mi<4;mi++){
    const int rb = tm*BM + wr + mi*16 + 4*lg;
    #pragma unroll
    for(int ni=0;ni<4;ni++){
      const int col = tn*BM + wc + ni*16 + lr;
      f32x4 a = acc[mi][ni];
      #pragma unroll
      for(int j=0;j<4;j++){
        int r = rb + j;
        if (r < M){
          if (EPI==0){
            outb[(size_t)r*ldo + ocol + col] = f2bf(a[j]);
          } else if (EPI==1){
            size_t idx=(size_t)r*ldo + col;
            outf[idx] = resid[idx] + a[j];
          } else if (EPI==2){
            float v=a[j]+biasb[(size_t)e*ldbias+col];
            v=v/(1.f+__expf(-v));
            outb[(size_t)(O+r)*ldo + col]=f2bf(v);
          } else {
            outb[(size_t)(O+r)*ldo + col]=f2bf(a[j]+biasb[(size_t)e*ldbias+col]);
          }
        }
      }
    }
  }
}

// ---------------- fused RoPE + V-transpose ----------------
__global__ __launch_bounds__(256) void ropeV_kernel(short* __restrict__ QKV,
    short* __restrict__ VT)
{
  const int id=blockIdx.x;
  const int tid=threadIdx.x;
  __shared__ short tls[32][33];
  if(id<1024){
    const int z=id>>7, b=z>>2, kvh=z&3;
    const int s0=(id&63)*32, d0=((id>>6)&1)*32;
    const int tx=tid&31, ty=tid>>5;
    #pragma unroll
    for(int i=0;i<4;i++)
      tls[ty+i*8][tx]=QKV[(size_t)(b*2048+s0+ty+i*8)*1536+1280+kvh*64+d0+tx];
    __syncthreads();
    #pragma unroll
    for(int i=0;i<4;i++)
      VT[((size_t)(b*4+kvh)*64+d0+ty+i*8)*2048+s0+tx]=tls[tx][ty+i*8];
    return;
  }
  int t=(id-1024)*256+tid;
  if(t>=2621440) return;
  size_t addr; int s,i;
  if(t<2097152){                  // Q
    i=t&31; int rh=t>>5; int bs=rh>>4, h=rh&15; s=bs&2047;
    addr=(size_t)bs*1536+h*64+2*i;
  }else{                          // K
    t-=2097152;
    i=t&31; int rh=t>>5; int bs=rh>>2, h=rh&3; s=bs&2047;
    addr=(size_t)bs*1536+1024+h*64+2*i;
  }
  float inv=__expf(-(float)i*0.28782313662425572f); // ln(10000)/32
  float ang=(float)s*inv;
  float c=__cosf(ang), sn=__sinf(ang);
  float xe=bf2f(QKV[addr]), xo=bf2f(QKV[addr+1]);
  QKV[addr]  =f2bf(xe*c-xo*sn);
  QKV[addr+1]=f2bf(xo*c+xe*sn);
}

// ---------------- causal GQA flash attention v3 (load-balanced) ----------------
__global__ __launch_bounds__(256) void attn_kernel(
    const short* __restrict__ QKV, const short* __restrict__ VT,
    short* __restrict__ O)
{
  const int b=blockIdx.z;
  const int qt = b==0 ? (int)blockIdx.x : 15-(int)blockIdx.x;
  const int h=blockIdx.y;
  const int kvh=h>>2;
  const int tid=threadIdx.x;
  const int w=tid>>6, lane=tid&63;
  const int lr=lane&15, lg=lane>>4;
  const int q0w=qt*128+w*32;

  __shared__ short Ks[64*64];
  __shared__ short Vs[64*64];
  __shared__ short Ps[4][32][72];

  short8 qf[2][2];
  #pragma unroll
  for(int qb=0;qb<2;qb++)
    #pragma unroll
    for(int ks=0;ks<2;ks++)
      qf[qb][ks]=*(const short8*)(QKV+(size_t)(b*2048+q0w+qb*16+lr)*1536+h*64+ks*32+lg*8);

  f32x4 o[2][4];
  float mj[2][4], lj[2][4];
  #pragma unroll
  for(int qb=0;qb<2;qb++)
    #pragma unroll
    for(int j=0;j<4;j++){
      mj[qb][j]=NEG_INF; lj[qb][j]=0.f;
      #pragma unroll
      for(int db=0;db<4;db++) o[qb][db]=(f32x4){0.f,0.f,0.f,0.f};
    }

  const int c1=w*64+lane;
  const int r1=c1>>3, swz=((c1&7)^(r1&7))*8;
  const short* gKb = QKV + 1024 + kvh*64 + (size_t)r1*1536 + swz;
  const short* gVb = VT + ((size_t)(b*4+kvh)*64 + r1)*2048 + swz;
  short* lK1=Ks+w*512; short* lK2=Ks+2048+w*512;
  short* lV1=Vs+w*512; short* lV2=Vs+2048+w*512;

  auto stage=[&](int kv0){
    const short* gK = gKb + (size_t)(b*2048+kv0)*1536;
    gload16(gK, lK1);
    gload16(gK + (size_t)32*1536, lK2);
    const short* gV = gVb + kv0;
    gload16(gV, lV1);
    gload16(gV + (size_t)32*2048, lV2);
  };

  const int kvend=qt*128+127;
  stage(0);
  for(int kv0=0;kv0<=kvend;kv0+=64){
    __syncthreads();
    const bool act = (kv0 <= q0w+31);
    short8 kf[4][2], vf[4][2];
    if(act){
      #pragma unroll
      for(int nb=0;nb<4;nb++)
        #pragma unroll
        for(int ks=0;ks<2;ks++)
          kf[nb][ks]=*(const short8*)(Ks+(nb*16+lr)*64+(((ks*4+lg)^(lr&7))*8));
      #pragma unroll
      for(int db=0;db<4;db++)
        #pragma unroll
        for(int ks=0;ks<2;ks++)
          vf[db][ks]=*(const short8*)(Vs+(db*16+lr)*64+(((ks*4+lg)^(lr&7))*8));
    }
    __syncthreads();
    if(kv0+64<=kvend) stage(kv0+64);
    if(!act) continue;

    f32x4 s[2][4];
    #pragma unroll
    for(int qb=0;qb<2;qb++)
      #pragma unroll
      for(int nb=0;nb<4;nb++){
        f32x4 t=(f32x4){0.f,0.f,0.f,0.f};
        t=MFMA16(qf[qb][0],kf[nb][0],t);
        t=MFMA16(qf[qb][1],kf[nb][1],t);
        s[qb][nb]=t;
      }

    const bool edge = (kv0+63 > q0w);
    float tmx[2][4];
    #pragma unroll
    for(int qb=0;qb<2;qb++)
      #pragma unroll
      for(int j=0;j<4;j++){
        float mx=NEG_INF;
        #pragma unroll
        for(int nb=0;nb<4;nb++){
          float v=s[qb][nb][j]*0.125f;
          if(edge){
            if(kv0+nb*16+lr > q0w+qb*16+4*lg+j) v=NEG_INF;
          }
          s[qb][nb][j]=v;
          mx=fmaxf(mx,v);
        }
        tmx[qb][j]=mx;
      }
    #pragma unroll
    for(int qb=0;qb<2;qb++)
      #pragma unroll
      for(int j=0;j<4;j++){
        #pragma unroll
        for(int od=1;od<16;od<<=1) tmx[qb][j]=fmaxf(tmx[qb][j],__shfl_xor(tmx[qb][j],od,64));
      }
    #pragma unroll
    for(int qb=0;qb<2;qb++)
      #pragma unroll
      for(int j=0;j<4;j++){
        float mn=fmaxf(mj[qb][j],tmx[qb][j]);
        float al=__expf(mj[qb][j]-mn);
        mj[qb][j]=mn;
        float rs=0.f;
        #pragma unroll
        for(int nb=0;nb<4;nb++){
          float pv=__expf(s[qb][nb][j]-mn);
          s[qb][nb][j]=pv;
          rs+=pv;
        }
        #pragma unroll
        for(int od=1;od<16;od<<=1) rs+=__shfl_xor(rs,od,64);
        lj[qb][j]=lj[qb][j]*al+rs;
        #pragma unroll
        for(int db=0;db<4;db++) o[qb][db][j]*=al;
      }
    #pragma unroll
    for(int qb=0;qb<2;qb++)
      #pragma unroll
      for(int nb=0;nb<4;nb++)
        #pragma unroll
        for(int j=0;j<4;j++)
          Ps[w][qb*16+4*lg+j][nb*16+lr]=f2bf(s[qb][nb][j]);
    short8 pa[2][2];
    #pragma unroll
    for(int qb=0;qb<2;qb++)
      #pragma unroll
      for(int ks=0;ks<2;ks++)
        pa[qb][ks]=*(const short8*)(&Ps[w][qb*16+lr][ks*32+lg*8]);
    #pragma unroll
    for(int qb=0;qb<2;qb++)
      #pragma unroll
      for(int db=0;db<4;db++){
        o[qb][db]=MFMA16(pa[qb][0],vf[db][0],o[qb][db]);
        o[qb][db]=MFMA16(pa[qb][1],vf[db][1],o[qb][db]);
      }
  }

  #pragma unroll
  for(int qb=0;qb<2;qb++)
    #pragma unroll
    for(int j=0;j<4;j++){
      const int qpos=q0w+qb*16+4*lg+j;
      const float inv=1.f/lj[qb][j];
      size_t base=(size_t)(b*2048+qpos)*DM+h*64;
      #pragma unroll
      for(int db=0;db<4;db++)
        O[base+db*16+lr]=f2bf(o[qb][db][j]*inv);
    }
}

// ---------------- fused RMSNorm-2 + router (NO atomics) ----------------
__global__ __launch_bounds__(256) void rms2_router(
    const float* __restrict__ xmid, const float* __restrict__ n2w,
    const float* __restrict__ gate_w, const float* __restrict__ gate_b,
    const float* __restrict__ noise_w, const float* __restrict__ noise_b,
    const float* __restrict__ rnoise,
    short* __restrict__ h2out,
    int* __restrict__ tokE, float* __restrict__ tokS)
{
  const int t=blockIdx.x, tid=threadIdx.x;
  const float4 xv=((const float4*)(xmid+(size_t)t*DM))[tid];
  float s=xv.x*xv.x+xv.y*xv.y+xv.z*xv.z+xv.w*xv.w;
  #pragma unroll
  for(int o=32;o;o>>=1) s+=__shfl_down(s,o,64);
  __shared__ float red[4];
  if((tid&63)==0) red[tid>>6]=s;
  __syncthreads();
  const float r=rsqrtf((red[0]+red[1]+red[2]+red[3])*(1.f/DM)+1e-8f);
  const float4 wv=((const float4*)n2w)[tid];
  float hreg[4]={wv.x*xv.x*r, wv.y*xv.y*r, wv.z*xv.z*r, wv.w*xv.w*r};
  short* op=h2out+(size_t)t*DM+tid*4;
  op[0]=f2bf(hreg[0]); op[1]=f2bf(hreg[1]);
  op[2]=f2bf(hreg[2]); op[3]=f2bf(hreg[3]);

  float acc[16];
  #pragma unroll
  for(int e=0;e<16;e++) acc[e]=0.f;
  #pragma unroll
  for(int i=0;i<4;i++){
    int d=tid*4+i;
    const float* gwr=gate_w+(size_t)d*8;
    const float* nwr=noise_w+(size_t)d*8;
    #pragma unroll
    for(int e=0;e<8;e++){ acc[e]+=hreg[i]*gwr[e]; acc[8+e]+=hreg[i]*nwr[e]; }
  }
  #pragma unroll
  for(int e=0;e<16;e++){
    #pragma unroll
    for(int o=32;o;o>>=1) acc[e]+=__shfl_down(acc[e],o,64);
  }
  __shared__ float red2[4][16];
  if((tid&63)==0){
    #pragma unroll
    for(int e=0;e<16;e++) red2[tid>>6][e]=acc[e];
  }
  __syncthreads();
  if(tid==0){
    float lgt[8];
    #pragma unroll
    for(int e=0;e<8;e++){
      float g =red2[0][e]+red2[1][e]+red2[2][e]+red2[3][e];
      float nz=red2[0][8+e]+red2[1][8+e]+red2[2][8+e]+red2[3][8+e];
      lgt[e]=g+gate_b[e]+nz+noise_b[e]+rnoise[(size_t)t*8+e];
    }
    int i1=0;
    for(int e=1;e<8;e++) if(lgt[e]>lgt[i1]) i1=e;
    int i2=(i1==0)?1:0;
    for(int e=0;e<8;e++) if(e!=i1 && lgt[e]>lgt[i2]) i2=e;
    float e2=expf(lgt[i2]-lgt[i1]);
    float den=1.f+e2;
    tokE[2*t]=i1; tokE[2*t+1]=i2;
    tokS[2*t]=1.f/den; tokS[2*t+1]=e2/den;
  }
}

// ---------------- deterministic router scan (1 block, no atomics) ------------
// 256 threads x 16 tokens. LDS per-thread histograms + score sums; 8-thread
// exclusive prefix across threads -> cnt/off; slot = off[e]+prefix+local rank.
// Replaces scan_aux + scatter_kernel. Also computes aux loss.
__global__ __launch_bounds__(256) void router_scan(
    const int* __restrict__ tokE, const float* __restrict__ tokS,
    int* __restrict__ cnt, int* __restrict__ off,
    int* __restrict__ tokL, int* __restrict__ slotOf,
    float* __restrict__ auxout)
{
  const int tid=threadIdx.x;
  __shared__ int   hist[256][8];
  __shared__ float simp[256][8];
  __shared__ int   cnt_s[8];
  __shared__ int   off_s[8];
  __shared__ float imp_s[8];
  #pragma unroll
  for(int e=0;e<8;e++){ hist[tid][e]=0; simp[tid][e]=0.f; }
  __syncthreads();
  const int base=tid*16;
  for(int k=0;k<16;k++){
    const int t=base+k;
    #pragma unroll
    for(int j=0;j<2;j++){
      int e=tokE[2*t+j];
      hist[tid][e]+=1;
      simp[tid][e]+=tokS[2*t+j];
    }
  }
  __syncthreads();
  if(tid<8){
    int run=0; float fs=0.f;
    for(int u=0;u<256;u++){
      int c=hist[u][tid];
      hist[u][tid]=run;          // exclusive prefix for thread u, expert tid
      run+=c;
      fs+=simp[u][tid];
    }
    cnt_s[tid]=run; cnt[tid]=run;
    imp_s[tid]=fs;
  }
  __syncthreads();
  if(tid==0){
    int o=0;
    #pragma unroll
    for(int e=0;e<8;e++){ off_s[e]=o; off[e]=o; o+=cnt_s[e]; }
    float u=0.125f, s=0.f;
    for(int e=0;e<8;e++) s+=u*(logf(u)-logf(imp_s[e]*(1.f/4096.f)+1e-8f));
    auxout[0]=s;
  }
  __syncthreads();
  for(int k=0;k<16;k++){
    const int t=base+k;
    #pragma unroll
    for(int j=0;j<2;j++){
      int e=tokE[2*t+j];
      int rnk=hist[tid][e];
      hist[tid][e]=rnk+1;
      int slot=off_s[e]+rnk;
      tokL[slot]=t;
      slotOf[2*t+j]=slot;
    }
  }
}

// ---------------- combine: dout[t] += s1*eo[slot1] + s2*eo[slot2] (eo bf16) ----
__global__ __launch_bounds__(256) void combine_kernel(const short* __restrict__ eo,
    const int* __restrict__ slotOf, const float* __restrict__ tokS,
    float* __restrict__ dout)
{
  const int t=blockIdx.x, d=threadIdx.x*4;
  const int s1=slotOf[2*t], s2=slotOf[2*t+1];
  const float w1=tokS[2*t], w2=tokS[2*t+1];
  float4 o=*(float4*)(dout+(size_t)t*DM+d);
  const short4 e1=*(const short4*)(eo+(size_t)s1*DM+d);
  const short4 e2=*(const short4*)(eo+(size_t)s2*DM+d);
  o.x+=w1*bf2f(e1.x)+w2*bf2f(e2.x);
  o.y+=w1*bf2f(e1.y)+w2*bf2f(e2.y);
  o.z+=w1*bf2f(e1.z)+w2*bf2f(e2.z);
  o.w+=w1*bf2f(e1.w)+w2*bf2f(e2.w);
  *(float4*)(dout+(size_t)t*DM+d)=o;
}

extern "C" void kernel_launch(void* const* d_in, const int* in_sizes, int n_in,
                              void* d_out, int out_size, void* d_ws, size_t ws_size,
                              hipStream_t stream)
{
  const float* x   =(const float*)d_in[0];
  const float* rn  =(const float*)d_in[1];
  const float* n1w =(const float*)d_in[2];
  const float* n2w =(const float*)d_in[3];
  const float* wq  =(const float*)d_in[4];
  const float* wk  =(const float*)d_in[5];
  const float* wv  =(const float*)d_in[6];
  const float* wo  =(const float*)d_in[7];
  const float* gw  =(const float*)d_in[8];
  const float* gb  =(const float*)d_in[9];
  const float* nw  =(const float*)d_in[10];
  const float* nb  =(const float*)d_in[11];
  const float* ew1 =(const float*)d_in[12];
  const float* eb1 =(const float*)d_in[13];
  const float* ew2 =(const float*)d_in[14];
  const float* eb2 =(const float*)d_in[15];
  float* dout=(float*)d_out;

  char* p=(char*)d_ws;
  auto take=[&](size_t n){ char* q=p; p+=(n+255)&~(size_t)255; return q; };
  short* h1    =(short*)take((size_t)TKN*DM*2);
  short* wqkvT =(short*)take((size_t)1536*DM*2);
  short* woT   =(short*)take((size_t)DM*DM*2);
  short* ew1T  =(short*)take((size_t)NE*DFF*DM*2);
  short* ew2T  =(short*)take((size_t)NE*DM*DFF*2);
  short* QKV   =(short*)take((size_t)TKN*1536*2);
  short* VTb   =(short*)take((size_t)8*64*2048*2);
  short* Ob    =(short*)take((size_t)TKN*DM*2);
  short* hh    =(short*)take((size_t)2*TKN*DFF*2);
  short* eoB   =(short*)take((size_t)2*TKN*DM*2);
  int*   tokE  =(int*)take((size_t)TKN*2*4);
  float* tokS  =(float*)take((size_t)TKN*2*4);
  int*   tokL  =(int*)take((size_t)2*TKN*4);
  int*   slotOf=(int*)take((size_t)TKN*2*4);
  int*   cnt   =(int*)take(256);
  int*   off   =cnt+8;

  rms1_kernel<<<TKN,256,0,stream>>>(x,n1w,h1);
  transpW4<<<dim3(32,16,4),256,0,stream>>>(wq,wk,wv,wo,wqkvT,woT);
  transpEW<<<dim3(128,32,8),256,0,stream>>>(ew1,ew2,ew1T,ew2T);

  // QKV projection: [4096][1536]
  gemm128k<0,false,false><<<dim3(12,32),256,0,stream>>>(
      h1,wqkvT,TKN,1536,DM,0, nullptr,nullptr,nullptr,
      QKV,1536,0, nullptr,nullptr, nullptr,0);
  ropeV_kernel<<<11264,256,0,stream>>>(QKV,VTb);
  attn_kernel<<<dim3(16,16,2),256,0,stream>>>(QKV,VTb,Ob);
  // O projection + residual
  gemm128k<1,false,false><<<dim3(8,32),256,0,stream>>>(
      Ob,woT,TKN,DM,DM,0, nullptr,nullptr,nullptr,
      nullptr,DM,0, dout,x, nullptr,0);

  // fused rms2 + router (no atomics), then deterministic scan
  rms2_router<<<TKN,256,0,stream>>>(dout,n2w,gw,gb,nw,nb,rn,h1,tokE,tokS);
  router_scan<<<1,256,0,stream>>>(tokE,tokS,cnt,off,tokL,slotOf,
                                  dout+(size_t)TKN*DM);

  // MoE GEMM1: hh = silu(h2[tokL] @ ew1 + eb1)
  gemm128k<2,true,true><<<dim3(32,32,8),256,0,stream>>>(
      h1,ew1T,0,DFF,DM,DFF*DM, cnt,off,tokL,
      hh,DFF,0, nullptr,nullptr, eb1,DFF);
  // MoE GEMM2: eo = hh @ ew2 + eb2   (bf16 output)
  gemm128k<3,false,true><<<dim3(8,32,8),256,0,stream>>>(
      hh,ew2T,0,DM,DFF,DM*DFF, cnt,off,nullptr,
      eoB,DM,0, nullptr,nullptr, eb2,DM);
  combine_kernel<<<TKN,256,0,stream>>>(eoB,slotOf,tokS,dout);
  (void)in_sizes;(void)n_in;(void)out_size;(void)ws_size;
}